// Round 3
// baseline (123.856 us; speedup 1.0000x reference)
//
#include <hip/hip_runtime.h>

#define N_NODES 8192
#define DOUT    512
#define LOG2E   1.4426950408889634f
#define SQRT3   1.7320508075688772f

// raw v_exp_f32 (D = 2^S0) — single trans-pipe instruction
__device__ __forceinline__ float exp2_raw(float x) {
    float r;
    asm("v_exp_f32 %0, %1" : "=v"(r) : "v"(x));
    return r;
}

// ws float layout: aux[32] at 0   (G*log2e [0..8], g0*log2e [9..11], Cmax partials [12..19])
//                  flagT (unsigned) at ws[32]
//                  T[512*8] at ws+64 (R3[3], h, M3[3], pad) — 256 B offset, 16B aligned

// ---------------- Kernel A: aux only (small) + flag init ----------------
// blocks 0..7  -> aux[12+b]: partial max |node component| over 1024 nodes
// blocks 8..19 -> aux[o]: G = Wq3^T Wk3 (o<9), g0 = Wq3^T kc (o=9..11), both *log2e
__global__ __launch_bounds__(256) void kA_aux(
    const float* __restrict__ nodes, const float* __restrict__ centre,
    const float* __restrict__ Wq, const float* __restrict__ Wk,
    const float* __restrict__ bk,
    float* __restrict__ aux, unsigned* __restrict__ flagT)
{
    __shared__ float red[4];
    const int tid = threadIdx.x, lane = tid & 63, wv = tid >> 6;
    const int b = blockIdx.x;
    if (b == 0 && tid == 0) *flagT = 0u;   // visible to kernel B at dispatch boundary
    const float c0 = centre[0], c1 = centre[1], c2 = centre[2];

    if (b < 8) {
        const float4* src = (const float4*)nodes + (size_t)b * 768;
        float m = 0.f;
        #pragma unroll
        for (int i = 0; i < 3; ++i) {
            float4 v = src[tid + 256*i];
            m = fmaxf(m, fmaxf(fmaxf(fabsf(v.x), fabsf(v.y)),
                               fmaxf(fabsf(v.z), fabsf(v.w))));
        }
        #pragma unroll
        for (int off = 32; off; off >>= 1) m = fmaxf(m, __shfl_xor(m, off));
        if (lane == 0) red[wv] = m;
        __syncthreads();
        if (tid == 0)
            aux[12 + b] = fmaxf(fmaxf(red[0], red[1]), fmaxf(red[2], red[3]));
    } else {
        const int o = b - 8;   // 0..11
        float acc = 0.f;
        if (o < 9) {
            int ra = o / 3, cb = o - ra*3;
            #pragma unroll
            for (int it = 0; it < 2; ++it) {
                int s = it*256 + tid;
                acc = fmaf(Wq[s*6+ra], Wk[s*6+cb], acc);
            }
        } else {
            int ra = o - 9;
            #pragma unroll
            for (int it = 0; it < 2; ++it) {
                int s = it*256 + tid;
                float kc = fmaf(Wk[s*6+3], c0, fmaf(Wk[s*6+4], c1,
                           fmaf(Wk[s*6+5], c2, bk[s])));
                acc = fmaf(Wq[s*6+ra], kc, acc);
            }
        }
        #pragma unroll
        for (int off = 32; off; off >>= 1) acc += __shfl_xor(acc, off);
        if (lane == 0) red[wv] = acc;
        __syncthreads();
        if (tid == 0) aux[o] = (red[0]+red[1]+red[2]+red[3]) * LOG2E;
    }
}

// ---- K3 helpers: SoA staging (register transpose) + b128 inner loop ----

__device__ __forceinline__ void stage_load(const float4* __restrict__ src, int tid,
                                           float4 v[4][3]) {
    #pragma unroll
    for (int k = 0; k < 4; ++k) {
        int t = k*256 + tid;                 // triple index 0..1023
        v[k][0] = src[t*3+0];
        v[k][1] = src[t*3+1];
        v[k][2] = src[t*3+2];
    }
}

__device__ __forceinline__ void stage_write(float* __restrict__ lds, int tid,
                                            float4 v[4][3]) {
    #pragma unroll
    for (int k = 0; k < 4; ++k) {
        int t = k*256 + tid;
        float4 a = v[k][0], b = v[k][1], c = v[k][2];
        // a=(x0,y0,z0,x1) b=(y1,z1,x2,y2) c=(z2,x3,y3,z3)
        *(float4*)&lds[        t*4] = make_float4(a.x, a.w, b.z, c.y);  // X plane
        *(float4*)&lds[4096 +  t*4] = make_float4(a.y, b.x, b.w, c.z);  // Y plane
        *(float4*)&lds[8192 +  t*4] = make_float4(a.z, b.y, c.x, c.w);  // Z plane
    }
}

__device__ __forceinline__ void attn_tile(const float* __restrict__ lds, int lane,
    const float vx[4], const float vy[4], const float vz[4], const float bb[4],
    float S[4], float ax[4], float ay[4], float az[4])
{
    #pragma unroll 2
    for (int it = 0; it < 16; ++it) {
        int jj = it*256 + lane*4;
        float4 X = *(const float4*)&lds[jj];
        float4 Y = *(const float4*)&lds[4096 + jj];
        float4 Z = *(const float4*)&lds[8192 + jj];
        #pragma unroll
        for (int q = 0; q < 4; ++q) {
            float a0 = fmaf(vx[q],X.x, fmaf(vy[q],Y.x, fmaf(vz[q],Z.x, bb[q])));
            float a1 = fmaf(vx[q],X.y, fmaf(vy[q],Y.y, fmaf(vz[q],Z.y, bb[q])));
            float a2 = fmaf(vx[q],X.z, fmaf(vy[q],Y.z, fmaf(vz[q],Z.z, bb[q])));
            float a3 = fmaf(vx[q],X.w, fmaf(vy[q],Y.w, fmaf(vz[q],Z.w, bb[q])));
            float e0 = exp2_raw(a0);
            float e1 = exp2_raw(a1);
            float e2 = exp2_raw(a2);
            float e3 = exp2_raw(a3);
            S[q] += e0; ax[q]=fmaf(e0,X.x,ax[q]); ay[q]=fmaf(e0,Y.x,ay[q]); az[q]=fmaf(e0,Z.x,az[q]);
            S[q] += e1; ax[q]=fmaf(e1,X.y,ax[q]); ay[q]=fmaf(e1,Y.y,ay[q]); az[q]=fmaf(e1,Z.y,az[q]);
            S[q] += e2; ax[q]=fmaf(e2,X.z,ax[q]); ay[q]=fmaf(e2,Y.z,ay[q]); az[q]=fmaf(e2,Z.z,az[q]);
            S[q] += e3; ax[q]=fmaf(e3,X.w,ax[q]); ay[q]=fmaf(e3,Y.w,ay[q]); az[q]=fmaf(e3,Z.w,az[q]);
        }
    }
}

// ---------------- Kernel B: T rows (blocks 0..127) + attention (128..639) ----------------
// T-writers signal via release atomics; attention blocks acquire-poll ONLY at the
// epilogue (~6 us in), by which time T (~2 us, overlapped) is long done.
// Deadlock-safe: 48 KB LDS -> 3 blocks/CU -> 768 resident slots >= 640 blocks.
__global__ __launch_bounds__(256, 3) void kB_main(
    const float* __restrict__ nodes, const float* __restrict__ centre,
    const float* __restrict__ Wq, const float* __restrict__ bq,
    const float* __restrict__ Wk, const float* __restrict__ bk,
    const float* __restrict__ Wv, const float* __restrict__ bv,
    const float* __restrict__ aux, float* __restrict__ T,
    unsigned* __restrict__ flagT, float* __restrict__ out)
{
    __shared__ float lds[12288];   // SoA: X[0..4095], Y[4096..8191], Z[8192..12287]
    const int tid = threadIdx.x, lane = tid & 63, wv = tid >> 6;

    if (blockIdx.x < 128) {
        // ---- T row r = blockIdx.x*4 + wv (one wave per row) ----
        const int r = blockIdx.x*4 + wv;
        const float c0 = centre[0], c1 = centre[1], c2 = centre[2];
        const float* wvq = Wv + (size_t)r * 1024;   // Wv[r, :512]; +512 = Wv_k
        float m0=0.f,m1=0.f,m2=0.f,uc=0.f,r0=0.f,r1=0.f,r2=0.f,rc=0.f;
        const int s0 = lane*8;
        #pragma unroll
        for (int h = 0; h < 2; ++h) {
            const int sb = s0 + h*4;                  // 4 consecutive s per half
            float4 a4 = *(const float4*)(wvq + sb);
            float4 b4 = *(const float4*)(wvq + 512 + sb);
            float4 q_[6], k_[6];
            #pragma unroll
            for (int j = 0; j < 6; ++j) {
                q_[j] = ((const float4*)(Wq + sb*6))[j];
                k_[j] = ((const float4*)(Wk + sb*6))[j];
            }
            float4 bq4 = *(const float4*)(bq + sb);
            float4 bk4 = *(const float4*)(bk + sb);
            const float* qf = (const float*)q_;
            const float* kf = (const float*)k_;
            const float* af = (const float*)&a4;
            const float* bf = (const float*)&b4;
            const float* bqf = (const float*)&bq4;
            const float* bkf = (const float*)&bk4;
            #pragma unroll
            for (int i = 0; i < 4; ++i) {
                float a = af[i], w = bf[i];
                float kcs = fmaf(kf[i*6+3], c0, fmaf(kf[i*6+4], c1,
                            fmaf(kf[i*6+5], c2, bkf[i])));
                float us  = fmaf(qf[i*6+3], c0, fmaf(qf[i*6+4], c1,
                            fmaf(qf[i*6+5], c2, bqf[i])));
                m0 = fmaf(a, qf[i*6+0], m0);
                m1 = fmaf(a, qf[i*6+1], m1);
                m2 = fmaf(a, qf[i*6+2], m2);
                uc = fmaf(a, us, uc);
                r0 = fmaf(w, kf[i*6+0], r0);
                r1 = fmaf(w, kf[i*6+1], r1);
                r2 = fmaf(w, kf[i*6+2], r2);
                rc = fmaf(w, kcs, rc);
            }
        }
        #pragma unroll
        for (int off = 32; off; off >>= 1) {
            m0 += __shfl_xor(m0, off); m1 += __shfl_xor(m1, off);
            m2 += __shfl_xor(m2, off); uc += __shfl_xor(uc, off);
            r0 += __shfl_xor(r0, off); r1 += __shfl_xor(r1, off);
            r2 += __shfl_xor(r2, off); rc += __shfl_xor(rc, off);
        }
        if (lane == 0) {
            float kcr = fmaf(Wk[r*6+3], c0, fmaf(Wk[r*6+4], c1,
                        fmaf(Wk[r*6+5], c2, bk[r])));
            T[r*8+0] = Wk[r*6+0] + r0;
            T[r*8+1] = Wk[r*6+1] + r1;
            T[r*8+2] = Wk[r*6+2] + r2;
            T[r*8+3] = kcr + rc + uc + bv[r];
            T[r*8+4] = m0; T[r*8+5] = m1; T[r*8+6] = m2; T[r*8+7] = 0.f;
            // release: orders this thread's T-row stores before the count
            __hip_atomic_fetch_add(flagT, 1u, __ATOMIC_RELEASE,
                                   __HIP_MEMORY_SCOPE_AGENT);
        }
        return;
    }

    // ---- attention rows; ibase over blocks 128..639 ----
    const int ibase = ((blockIdx.x - 128) * 4 + wv) * 4;

    const float G00=aux[0],G01=aux[1],G02=aux[2];
    const float G10=aux[3],G11=aux[4],G12=aux[5];
    const float G20=aux[6],G21=aux[7],G22=aux[8];
    const float g0=aux[9],g1=aux[10],g2=aux[11];
    float C = aux[12];
    #pragma unroll
    for (int b = 1; b < 8; ++b) C = fmaxf(C, aux[12+b]);
    const float Nbound = SQRT3 * C;   // |n_j| <= sqrt(3) * max|component|

    float nx_[4], ny_[4], nz_[4], vx[4], vy[4], vz[4], bb[4];
    float S[4], ax[4], ay[4], az[4];
    #pragma unroll
    for (int q = 0; q < 4; ++q) {
        int i = ibase + q;
        float x = nodes[3*i], y = nodes[3*i+1], z = nodes[3*i+2];
        nx_[q]=x; ny_[q]=y; nz_[q]=z;
        float a = fmaf(G00,x, fmaf(G01,y, fmaf(G02,z, g0)));
        float b = fmaf(G10,x, fmaf(G11,y, fmaf(G12,z, g1)));
        float c = fmaf(G20,x, fmaf(G21,y, fmaf(G22,z, g2)));
        vx[q]=a; vy[q]=b; vz[q]=c;
        // Cauchy-Schwarz bound (log2 scale): arg <= ~0 always; shift cancels in softmax
        bb[q] = -sqrtf(fmaf(a,a, fmaf(b,b, c*c))) * Nbound;
        S[q]=0.f; ax[q]=0.f; ay[q]=0.f; az[q]=0.f;
    }

    // tile 0 stage, then ISSUE tile-1 loads before compute (waitcnt lands at write)
    float4 s0[4][3], s1[4][3];
    stage_load((const float4*)nodes, tid, s0);
    stage_write(lds, tid, s0);
    stage_load((const float4*)(nodes + 12288), tid, s1);
    __syncthreads();
    attn_tile(lds, lane, vx, vy, vz, bb, S, ax, ay, az);
    __syncthreads();
    stage_write(lds, tid, s1);
    __syncthreads();
    attn_tile(lds, lane, vx, vy, vz, bb, S, ax, ay, az);

    #pragma unroll
    for (int q = 0; q < 4; ++q) {
        #pragma unroll
        for (int off = 32; off; off >>= 1) {
            S[q]  += __shfl_xor(S[q],  off);
            ax[q] += __shfl_xor(ax[q], off);
            ay[q] += __shfl_xor(ay[q], off);
            az[q] += __shfl_xor(az[q], off);
        }
        float inv = 1.f / fmaxf(S[q], 1e-35f);
        ax[q] *= inv; ay[q] *= inv; az[q] *= inv;   // ā_i
    }

    // wait for T (acquire; normally already satisfied — T finished ~4 us ago)
    while (__hip_atomic_load(flagT, __ATOMIC_ACQUIRE,
                             __HIP_MEMORY_SCOPE_AGENT) < 512u)
        __builtin_amdgcn_s_sleep(2);

    // epilogue: out[i][d] = R3[d].n_i + M3[d].ā_i + h[d]; float2 stores (coalesced)
    const float4* T4 = (const float4*)T;
    #pragma unroll
    for (int t = 0; t < 4; ++t) {
        int d0 = t*128 + lane*2;
        float4 A0 = T4[2*d0+0], B0 = T4[2*d0+1];
        float4 A1 = T4[2*d0+2], B1 = T4[2*d0+3];
        #pragma unroll
        for (int q = 0; q < 4; ++q) {
            float v0 = fmaf(A0.x,nx_[q], fmaf(A0.y,ny_[q], fmaf(A0.z,nz_[q],
                       fmaf(B0.x,ax[q], fmaf(B0.y,ay[q], fmaf(B0.z,az[q], A0.w))))));
            float v1 = fmaf(A1.x,nx_[q], fmaf(A1.y,ny_[q], fmaf(A1.z,nz_[q],
                       fmaf(B1.x,ax[q], fmaf(B1.y,ay[q], fmaf(B1.z,az[q], A1.w))))));
            *(float2*)(out + (size_t)(ibase+q)*DOUT + d0) = make_float2(v0, v1);
        }
    }
}

extern "C" void kernel_launch(void* const* d_in, const int* in_sizes, int n_in,
                              void* d_out, int out_size, void* d_ws, size_t ws_size,
                              hipStream_t stream) {
    const float* nodes  = (const float*)d_in[0];
    const float* centre = (const float*)d_in[1];
    const float* Wq     = (const float*)d_in[2];
    const float* bq     = (const float*)d_in[3];
    const float* Wk     = (const float*)d_in[4];
    const float* bk     = (const float*)d_in[5];
    const float* Wv     = (const float*)d_in[6];
    const float* bv     = (const float*)d_in[7];

    float* ws   = (float*)(((uintptr_t)d_ws + 255) & ~(uintptr_t)255);
    float* aux  = ws;                      // 32 floats
    unsigned* flagT = (unsigned*)(ws + 32);
    float* T    = ws + 64;                 // 4096 floats, 256 B offset
    float* out  = (float*)d_out;

    hipLaunchKernelGGL(kA_aux, dim3(20), dim3(256), 0, stream,
                       nodes, centre, Wq, Wk, bk, aux, flagT);
    hipLaunchKernelGGL(kB_main, dim3(640), dim3(256), 0, stream,
                       nodes, centre, Wq, bq, Wk, bk, Wv, bv, aux, T, flagT, out);
}

// Round 4
// 112.352 us; speedup vs baseline: 1.1024x; 1.1024x over previous
//
#include <hip/hip_runtime.h>

#define N_NODES 8192
#define DOUT    512
#define LOG2E   1.4426950408889634f
#define SQRT3   1.7320508075688772f

// raw v_exp_f32 (D = 2^S0) — single trans-pipe instruction
__device__ __forceinline__ float exp2_raw(float x) {
    float r;
    asm("v_exp_f32 %0, %1" : "=v"(r) : "v"(x));
    return r;
}

// ws float layout: aux[32] at 0   (G*log2e [0..8], g0*log2e [9..11], Cmax partials [12..19])
//                  flagT (unsigned) at ws[32]
//                  T[512*8] at ws+64 (R3[3], h, M3[3], pad) — 256 B offset, 16B aligned

// ---------------- Kernel A: aux only (small) + flag init ----------------
// blocks 0..7  -> aux[12+b]: partial max |node component| over 1024 nodes
// blocks 8..19 -> aux[o]: G = Wq3^T Wk3 (o<9), g0 = Wq3^T kc (o=9..11), both *log2e
__global__ __launch_bounds__(256) void kA_aux(
    const float* __restrict__ nodes, const float* __restrict__ centre,
    const float* __restrict__ Wq, const float* __restrict__ Wk,
    const float* __restrict__ bk,
    float* __restrict__ aux, unsigned* __restrict__ flagT)
{
    __shared__ float red[4];
    const int tid = threadIdx.x, lane = tid & 63, wv = tid >> 6;
    const int b = blockIdx.x;
    if (b == 0 && tid == 0) *flagT = 0u;   // visible to kernel B at dispatch boundary
    const float c0 = centre[0], c1 = centre[1], c2 = centre[2];

    if (b < 8) {
        const float4* src = (const float4*)nodes + (size_t)b * 768;
        float m = 0.f;
        #pragma unroll
        for (int i = 0; i < 3; ++i) {
            float4 v = src[tid + 256*i];
            m = fmaxf(m, fmaxf(fmaxf(fabsf(v.x), fabsf(v.y)),
                               fmaxf(fabsf(v.z), fabsf(v.w))));
        }
        #pragma unroll
        for (int off = 32; off; off >>= 1) m = fmaxf(m, __shfl_xor(m, off));
        if (lane == 0) red[wv] = m;
        __syncthreads();
        if (tid == 0)
            aux[12 + b] = fmaxf(fmaxf(red[0], red[1]), fmaxf(red[2], red[3]));
    } else {
        const int o = b - 8;   // 0..11
        float acc = 0.f;
        if (o < 9) {
            int ra = o / 3, cb = o - ra*3;
            #pragma unroll
            for (int it = 0; it < 2; ++it) {
                int s = it*256 + tid;
                acc = fmaf(Wq[s*6+ra], Wk[s*6+cb], acc);
            }
        } else {
            int ra = o - 9;
            #pragma unroll
            for (int it = 0; it < 2; ++it) {
                int s = it*256 + tid;
                float kc = fmaf(Wk[s*6+3], c0, fmaf(Wk[s*6+4], c1,
                           fmaf(Wk[s*6+5], c2, bk[s])));
                acc = fmaf(Wq[s*6+ra], kc, acc);
            }
        }
        #pragma unroll
        for (int off = 32; off; off >>= 1) acc += __shfl_xor(acc, off);
        if (lane == 0) red[wv] = acc;
        __syncthreads();
        if (tid == 0) aux[o] = (red[0]+red[1]+red[2]+red[3]) * LOG2E;
    }
}

// ---- K3 helpers: SoA staging (register transpose) + b128 inner loop ----

__device__ __forceinline__ void stage_load(const float4* __restrict__ src, int tid,
                                           float4 v[4][3]) {
    #pragma unroll
    for (int k = 0; k < 4; ++k) {
        int t = k*256 + tid;                 // triple index 0..1023
        v[k][0] = src[t*3+0];
        v[k][1] = src[t*3+1];
        v[k][2] = src[t*3+2];
    }
}

__device__ __forceinline__ void stage_write(float* __restrict__ lds, int tid,
                                            float4 v[4][3]) {
    #pragma unroll
    for (int k = 0; k < 4; ++k) {
        int t = k*256 + tid;
        float4 a = v[k][0], b = v[k][1], c = v[k][2];
        // a=(x0,y0,z0,x1) b=(y1,z1,x2,y2) c=(z2,x3,y3,z3)
        *(float4*)&lds[        t*4] = make_float4(a.x, a.w, b.z, c.y);  // X plane
        *(float4*)&lds[4096 +  t*4] = make_float4(a.y, b.x, b.w, c.z);  // Y plane
        *(float4*)&lds[8192 +  t*4] = make_float4(a.z, b.y, c.x, c.w);  // Z plane
    }
}

__device__ __forceinline__ void attn_tile(const float* __restrict__ lds, int lane,
    const float vx[4], const float vy[4], const float vz[4], const float bb[4],
    float S[4], float ax[4], float ay[4], float az[4])
{
    #pragma unroll 2
    for (int it = 0; it < 16; ++it) {
        int jj = it*256 + lane*4;
        float4 X = *(const float4*)&lds[jj];
        float4 Y = *(const float4*)&lds[4096 + jj];
        float4 Z = *(const float4*)&lds[8192 + jj];
        #pragma unroll
        for (int q = 0; q < 4; ++q) {
            float a0 = fmaf(vx[q],X.x, fmaf(vy[q],Y.x, fmaf(vz[q],Z.x, bb[q])));
            float a1 = fmaf(vx[q],X.y, fmaf(vy[q],Y.y, fmaf(vz[q],Z.y, bb[q])));
            float a2 = fmaf(vx[q],X.z, fmaf(vy[q],Y.z, fmaf(vz[q],Z.z, bb[q])));
            float a3 = fmaf(vx[q],X.w, fmaf(vy[q],Y.w, fmaf(vz[q],Z.w, bb[q])));
            float e0 = exp2_raw(a0);
            float e1 = exp2_raw(a1);
            float e2 = exp2_raw(a2);
            float e3 = exp2_raw(a3);
            S[q] += e0; ax[q]=fmaf(e0,X.x,ax[q]); ay[q]=fmaf(e0,Y.x,ay[q]); az[q]=fmaf(e0,Z.x,az[q]);
            S[q] += e1; ax[q]=fmaf(e1,X.y,ax[q]); ay[q]=fmaf(e1,Y.y,ay[q]); az[q]=fmaf(e1,Z.y,az[q]);
            S[q] += e2; ax[q]=fmaf(e2,X.z,ax[q]); ay[q]=fmaf(e2,Y.z,ay[q]); az[q]=fmaf(e2,Z.z,az[q]);
            S[q] += e3; ax[q]=fmaf(e3,X.w,ax[q]); ay[q]=fmaf(e3,Y.w,ay[q]); az[q]=fmaf(e3,Z.w,az[q]);
        }
    }
}

// ---------------- Kernel B: fused T + attention, 512 blocks ----------------
// Blocks 0..127 first compute 4 T rows each (1 wave/row), release-add flagT;
// then ALL 512 blocks run attention (4 rows/wave). Epilogue acquire-polls flagT
// (reached ~7 us in; T finishes ~2 us in, overlapped under the other blocks).
// Deadlock-safe WITHOUT dispatch-order assumptions: launch_bounds(256,2) ->
// VGPR<=128 -> 2 blocks/CU; 48 KB LDS also allows >=2; 2*256 = 512 slots >=
// 512 blocks, so every block is resident from t=0.
__global__ __launch_bounds__(256, 2) void kB_main(
    const float* __restrict__ nodes, const float* __restrict__ centre,
    const float* __restrict__ Wq, const float* __restrict__ bq,
    const float* __restrict__ Wk, const float* __restrict__ bk,
    const float* __restrict__ Wv, const float* __restrict__ bv,
    const float* __restrict__ aux, float* __restrict__ T,
    unsigned* __restrict__ flagT, float* __restrict__ out)
{
    __shared__ float lds[12288];   // SoA: X[0..4095], Y[4096..8191], Z[8192..12287]
    const int tid = threadIdx.x, lane = tid & 63, wv = tid >> 6;

    if (blockIdx.x < 128) {
        // ---- T row r = blockIdx.x*4 + wv (one wave per row), then fall through ----
        const int r = blockIdx.x*4 + wv;
        const float c0 = centre[0], c1 = centre[1], c2 = centre[2];
        const float* wvq = Wv + (size_t)r * 1024;   // Wv[r, :512]; +512 = Wv_k
        float m0=0.f,m1=0.f,m2=0.f,uc=0.f,r0=0.f,r1=0.f,r2=0.f,rc=0.f;
        const int s0 = lane*8;
        #pragma unroll
        for (int h = 0; h < 2; ++h) {
            const int sb = s0 + h*4;                  // 4 consecutive s per half
            float4 a4 = *(const float4*)(wvq + sb);
            float4 b4 = *(const float4*)(wvq + 512 + sb);
            float4 q_[6], k_[6];
            #pragma unroll
            for (int j = 0; j < 6; ++j) {
                q_[j] = ((const float4*)(Wq + sb*6))[j];
                k_[j] = ((const float4*)(Wk + sb*6))[j];
            }
            float4 bq4 = *(const float4*)(bq + sb);
            float4 bk4 = *(const float4*)(bk + sb);
            const float* qf = (const float*)q_;
            const float* kf = (const float*)k_;
            const float* af = (const float*)&a4;
            const float* bf = (const float*)&b4;
            const float* bqf = (const float*)&bq4;
            const float* bkf = (const float*)&bk4;
            #pragma unroll
            for (int i = 0; i < 4; ++i) {
                float a = af[i], w = bf[i];
                float kcs = fmaf(kf[i*6+3], c0, fmaf(kf[i*6+4], c1,
                            fmaf(kf[i*6+5], c2, bkf[i])));
                float us  = fmaf(qf[i*6+3], c0, fmaf(qf[i*6+4], c1,
                            fmaf(qf[i*6+5], c2, bqf[i])));
                m0 = fmaf(a, qf[i*6+0], m0);
                m1 = fmaf(a, qf[i*6+1], m1);
                m2 = fmaf(a, qf[i*6+2], m2);
                uc = fmaf(a, us, uc);
                r0 = fmaf(w, kf[i*6+0], r0);
                r1 = fmaf(w, kf[i*6+1], r1);
                r2 = fmaf(w, kf[i*6+2], r2);
                rc = fmaf(w, kcs, rc);
            }
        }
        #pragma unroll
        for (int off = 32; off; off >>= 1) {
            m0 += __shfl_xor(m0, off); m1 += __shfl_xor(m1, off);
            m2 += __shfl_xor(m2, off); uc += __shfl_xor(uc, off);
            r0 += __shfl_xor(r0, off); r1 += __shfl_xor(r1, off);
            r2 += __shfl_xor(r2, off); rc += __shfl_xor(rc, off);
        }
        if (lane == 0) {
            float kcr = fmaf(Wk[r*6+3], c0, fmaf(Wk[r*6+4], c1,
                        fmaf(Wk[r*6+5], c2, bk[r])));
            T[r*8+0] = Wk[r*6+0] + r0;
            T[r*8+1] = Wk[r*6+1] + r1;
            T[r*8+2] = Wk[r*6+2] + r2;
            T[r*8+3] = kcr + rc + uc + bv[r];
            T[r*8+4] = m0; T[r*8+5] = m1; T[r*8+6] = m2; T[r*8+7] = 0.f;
            // release: orders this thread's T-row stores before the count
            __hip_atomic_fetch_add(flagT, 1u, __ATOMIC_RELEASE,
                                   __HIP_MEMORY_SCOPE_AGENT);
        }
        // fall through to attention (no return)
    }

    // ---- attention rows; all 512 blocks, 4 rows/wave ----
    const int ibase = (blockIdx.x * 4 + wv) * 4;

    const float G00=aux[0],G01=aux[1],G02=aux[2];
    const float G10=aux[3],G11=aux[4],G12=aux[5];
    const float G20=aux[6],G21=aux[7],G22=aux[8];
    const float g0=aux[9],g1=aux[10],g2=aux[11];
    float C = aux[12];
    #pragma unroll
    for (int b = 1; b < 8; ++b) C = fmaxf(C, aux[12+b]);
    const float Nbound = SQRT3 * C;   // |n_j| <= sqrt(3) * max|component|

    float nx_[4], ny_[4], nz_[4], vx[4], vy[4], vz[4], bb[4];
    float S[4], ax[4], ay[4], az[4];
    #pragma unroll
    for (int q = 0; q < 4; ++q) {
        int i = ibase + q;
        float x = nodes[3*i], y = nodes[3*i+1], z = nodes[3*i+2];
        nx_[q]=x; ny_[q]=y; nz_[q]=z;
        float a = fmaf(G00,x, fmaf(G01,y, fmaf(G02,z, g0)));
        float b = fmaf(G10,x, fmaf(G11,y, fmaf(G12,z, g1)));
        float c = fmaf(G20,x, fmaf(G21,y, fmaf(G22,z, g2)));
        vx[q]=a; vy[q]=b; vz[q]=c;
        // Cauchy-Schwarz bound (log2 scale): arg <= ~0 always; shift cancels in softmax
        bb[q] = -sqrtf(fmaf(a,a, fmaf(b,b, c*c))) * Nbound;
        S[q]=0.f; ax[q]=0.f; ay[q]=0.f; az[q]=0.f;
    }

    // tile 0 stage, then ISSUE tile-1 loads before compute (waitcnt lands at write)
    float4 s0v[4][3], s1v[4][3];
    stage_load((const float4*)nodes, tid, s0v);
    stage_write(lds, tid, s0v);
    stage_load((const float4*)(nodes + 12288), tid, s1v);
    __syncthreads();
    attn_tile(lds, lane, vx, vy, vz, bb, S, ax, ay, az);
    __syncthreads();
    stage_write(lds, tid, s1v);
    __syncthreads();
    attn_tile(lds, lane, vx, vy, vz, bb, S, ax, ay, az);

    #pragma unroll
    for (int q = 0; q < 4; ++q) {
        #pragma unroll
        for (int off = 32; off; off >>= 1) {
            S[q]  += __shfl_xor(S[q],  off);
            ax[q] += __shfl_xor(ax[q], off);
            ay[q] += __shfl_xor(ay[q], off);
            az[q] += __shfl_xor(az[q], off);
        }
        float inv = 1.f / fmaxf(S[q], 1e-35f);
        ax[q] *= inv; ay[q] *= inv; az[q] *= inv;   // ā_i
    }

    // wait for T: relaxed poll (cheap), one acquire fence on exit.
    // Normally already satisfied — T finished ~5 us before we get here.
    while (__hip_atomic_load(flagT, __ATOMIC_RELAXED,
                             __HIP_MEMORY_SCOPE_AGENT) < 512u)
        __builtin_amdgcn_s_sleep(8);
    __builtin_amdgcn_fence(__ATOMIC_ACQUIRE, "agent");

    // epilogue: out[i][d] = R3[d].n_i + M3[d].ā_i + h[d]; float2 stores (coalesced)
    const float4* T4 = (const float4*)T;
    #pragma unroll
    for (int t = 0; t < 4; ++t) {
        int d0 = t*128 + lane*2;
        float4 A0 = T4[2*d0+0], B0 = T4[2*d0+1];
        float4 A1 = T4[2*d0+2], B1 = T4[2*d0+3];
        #pragma unroll
        for (int q = 0; q < 4; ++q) {
            float v0 = fmaf(A0.x,nx_[q], fmaf(A0.y,ny_[q], fmaf(A0.z,nz_[q],
                       fmaf(B0.x,ax[q], fmaf(B0.y,ay[q], fmaf(B0.z,az[q], A0.w))))));
            float v1 = fmaf(A1.x,nx_[q], fmaf(A1.y,ny_[q], fmaf(A1.z,nz_[q],
                       fmaf(B1.x,ax[q], fmaf(B1.y,ay[q], fmaf(B1.z,az[q], A1.w))))));
            *(float2*)(out + (size_t)(ibase+q)*DOUT + d0) = make_float2(v0, v1);
        }
    }
}

extern "C" void kernel_launch(void* const* d_in, const int* in_sizes, int n_in,
                              void* d_out, int out_size, void* d_ws, size_t ws_size,
                              hipStream_t stream) {
    const float* nodes  = (const float*)d_in[0];
    const float* centre = (const float*)d_in[1];
    const float* Wq     = (const float*)d_in[2];
    const float* bq     = (const float*)d_in[3];
    const float* Wk     = (const float*)d_in[4];
    const float* bk     = (const float*)d_in[5];
    const float* Wv     = (const float*)d_in[6];
    const float* bv     = (const float*)d_in[7];

    float* ws   = (float*)(((uintptr_t)d_ws + 255) & ~(uintptr_t)255);
    float* aux  = ws;                      // 32 floats
    unsigned* flagT = (unsigned*)(ws + 32);
    float* T    = ws + 64;                 // 4096 floats, 256 B offset
    float* out  = (float*)d_out;

    hipLaunchKernelGGL(kA_aux, dim3(20), dim3(256), 0, stream,
                       nodes, centre, Wq, Wk, bk, aux, flagT);
    hipLaunchKernelGGL(kB_main, dim3(512), dim3(256), 0, stream,
                       nodes, centre, Wq, bq, Wk, bk, Wv, bv, aux, T, flagT, out);
}

// Round 5
// 96.765 us; speedup vs baseline: 1.2800x; 1.1611x over previous
//
#include <hip/hip_runtime.h>

#define N_NODES 8192
#define DOUT    512
#define LOG2E   1.4426950408889634f
#define SQRT3   1.7320508075688772f

// raw v_exp_f32 (D = 2^S0) — single trans-pipe instruction
__device__ __forceinline__ float exp2_raw(float x) {
    float r;
    asm("v_exp_f32 %0, %1" : "=v"(r) : "v"(x));
    return r;
}

// ws float layout: aux[32] at 0   (G*log2e [0..8], g0*log2e [9..11], Cmax partials [12..19])
//                  T[512*8] at ws+64 (R3[3], h, M3[3], pad) — 256 B offset, 16B aligned

// ---------------- K1: T table (blocks 0..127) + aux (blocks 128..147) ----------------
// T = Wv @ B where B = [Wq3|u ; Wk3|kc] (1024 x 4+4). Each T-block builds B once in
// LDS (16 KB) from a single Wq/Wk gather pass, then streams Wv coalesced (2 MB read
// exactly once chip-wide) with conflict-free ds_read_b128 of B. 4 rows/block, 1 wave/row.
__global__ __launch_bounds__(256) void k1_tables(
    const float* __restrict__ nodes, const float* __restrict__ centre,
    const float* __restrict__ Wq, const float* __restrict__ bq,
    const float* __restrict__ Wk, const float* __restrict__ bk,
    const float* __restrict__ Wv, const float* __restrict__ bv,
    float* __restrict__ T, float* __restrict__ aux)
{
    __shared__ float4 Bq_l[512];
    __shared__ float4 Bk_l[512];
    __shared__ float red[4];
    const int tid = threadIdx.x, lane = tid & 63, wv_ = tid >> 6;
    const float c0 = centre[0], c1 = centre[1], c2 = centre[2];

    if (blockIdx.x < 128) {
        // build B tables: B_k[s] = (Wk[s,0..2], kc_s), B_q[s] = (Wq[s,0..2], u_s)
        for (int t = tid; t < 512; t += 256) {
            const float2* wk2 = (const float2*)(Wk + t*6);  // rows 24B -> 8B aligned
            const float2* wq2 = (const float2*)(Wq + t*6);
            float2 k01 = wk2[0], k23 = wk2[1], k45 = wk2[2];
            float2 q01 = wq2[0], q23 = wq2[1], q45 = wq2[2];
            float kc = fmaf(k23.y, c0, fmaf(k45.x, c1, fmaf(k45.y, c2, bk[t])));
            float u  = fmaf(q23.y, c0, fmaf(q45.x, c1, fmaf(q45.y, c2, bq[t])));
            Bk_l[t] = make_float4(k01.x, k01.y, k23.x, kc);
            Bq_l[t] = make_float4(q01.x, q01.y, q23.x, u);
        }
        __syncthreads();

        // wave wv_ -> row r; lane-consecutive s: coalesced Wv loads (256B/wave),
        // conflict-free ds_read_b128 of B
        const int r = blockIdx.x*4 + wv_;
        const float* wvq = Wv + (size_t)r * 1024;   // Wv[r, :512]
        const float* wvk = wvq + 512;               // Wv[r, 512:]
        float m0=0.f,m1=0.f,m2=0.f,uc=0.f,r0=0.f,r1=0.f,r2=0.f,rc=0.f;
        #pragma unroll
        for (int i = 0; i < 8; ++i) {
            int s = i*64 + lane;
            float a = wvq[s];
            float b = wvk[s];
            float4 q4 = Bq_l[s];
            float4 k4 = Bk_l[s];
            m0 = fmaf(a, q4.x, m0); m1 = fmaf(a, q4.y, m1);
            m2 = fmaf(a, q4.z, m2); uc = fmaf(a, q4.w, uc);
            r0 = fmaf(b, k4.x, r0); r1 = fmaf(b, k4.y, r1);
            r2 = fmaf(b, k4.z, r2); rc = fmaf(b, k4.w, rc);
        }
        #pragma unroll
        for (int off = 32; off; off >>= 1) {
            m0 += __shfl_xor(m0, off); m1 += __shfl_xor(m1, off);
            m2 += __shfl_xor(m2, off); uc += __shfl_xor(uc, off);
            r0 += __shfl_xor(r0, off); r1 += __shfl_xor(r1, off);
            r2 += __shfl_xor(r2, off); rc += __shfl_xor(rc, off);
        }
        if (lane == 0) {
            float4 kr = Bk_l[r];   // (Wk3[r], kc_r)
            T[r*8+0] = kr.x + r0;
            T[r*8+1] = kr.y + r1;
            T[r*8+2] = kr.z + r2;
            T[r*8+3] = kr.w + rc + uc + bv[r];
            T[r*8+4] = m0; T[r*8+5] = m1; T[r*8+6] = m2; T[r*8+7] = 0.f;
        }
    } else if (blockIdx.x < 136) {
        // Cmax partial: max |component| over 1024 nodes (768 float4)
        const int b = blockIdx.x - 128;   // 0..7
        const float4* src = (const float4*)nodes + (size_t)b * 768;
        float m = 0.f;
        #pragma unroll
        for (int i = 0; i < 3; ++i) {
            float4 v = src[tid + 256*i];
            m = fmaxf(m, fmaxf(fmaxf(fabsf(v.x), fabsf(v.y)),
                               fmaxf(fabsf(v.z), fabsf(v.w))));
        }
        #pragma unroll
        for (int off = 32; off; off >>= 1) m = fmaxf(m, __shfl_xor(m, off));
        if (lane == 0) red[wv_] = m;
        __syncthreads();
        if (tid == 0)
            aux[12 + b] = fmaxf(fmaxf(red[0], red[1]), fmaxf(red[2], red[3]));
    } else {
        // G = Wq3^T Wk3 (o<9), g0 = Wq3^T kc (o=9..11), both *log2e
        const int o = blockIdx.x - 136;   // 0..11
        float acc = 0.f;
        if (o < 9) {
            int ra = o / 3, cb = o - ra*3;
            #pragma unroll
            for (int it = 0; it < 2; ++it) {
                int s = it*256 + tid;
                acc = fmaf(Wq[s*6+ra], Wk[s*6+cb], acc);
            }
        } else {
            int ra = o - 9;
            #pragma unroll
            for (int it = 0; it < 2; ++it) {
                int s = it*256 + tid;
                float kc = fmaf(Wk[s*6+3], c0, fmaf(Wk[s*6+4], c1,
                           fmaf(Wk[s*6+5], c2, bk[s])));
                acc = fmaf(Wq[s*6+ra], kc, acc);
            }
        }
        #pragma unroll
        for (int off = 32; off; off >>= 1) acc += __shfl_xor(acc, off);
        if (lane == 0) red[wv_] = acc;
        __syncthreads();
        if (tid == 0) aux[o] = (red[0]+red[1]+red[2]+red[3]) * LOG2E;
    }
}

// ---- K3 helpers: SoA staging (register transpose) + b128 inner loop ----

__device__ __forceinline__ void stage_load(const float4* __restrict__ src, int tid,
                                           float4 v[4][3]) {
    #pragma unroll
    for (int k = 0; k < 4; ++k) {
        int t = k*256 + tid;                 // triple index 0..1023
        v[k][0] = src[t*3+0];
        v[k][1] = src[t*3+1];
        v[k][2] = src[t*3+2];
    }
}

__device__ __forceinline__ void stage_write(float* __restrict__ lds, int tid,
                                            float4 v[4][3]) {
    #pragma unroll
    for (int k = 0; k < 4; ++k) {
        int t = k*256 + tid;
        float4 a = v[k][0], b = v[k][1], c = v[k][2];
        // a=(x0,y0,z0,x1) b=(y1,z1,x2,y2) c=(z2,x3,y3,z3)
        *(float4*)&lds[        t*4] = make_float4(a.x, a.w, b.z, c.y);  // X plane
        *(float4*)&lds[4096 +  t*4] = make_float4(a.y, b.x, b.w, c.z);  // Y plane
        *(float4*)&lds[8192 +  t*4] = make_float4(a.z, b.y, c.x, c.w);  // Z plane
    }
}

__device__ __forceinline__ void attn_tile(const float* __restrict__ lds, int lane,
    const float vx[4], const float vy[4], const float vz[4], const float bb[4],
    float S[4], float ax[4], float ay[4], float az[4])
{
    #pragma unroll 2
    for (int it = 0; it < 16; ++it) {
        int jj = it*256 + lane*4;
        float4 X = *(const float4*)&lds[jj];
        float4 Y = *(const float4*)&lds[4096 + jj];
        float4 Z = *(const float4*)&lds[8192 + jj];
        #pragma unroll
        for (int q = 0; q < 4; ++q) {
            float a0 = fmaf(vx[q],X.x, fmaf(vy[q],Y.x, fmaf(vz[q],Z.x, bb[q])));
            float a1 = fmaf(vx[q],X.y, fmaf(vy[q],Y.y, fmaf(vz[q],Z.y, bb[q])));
            float a2 = fmaf(vx[q],X.z, fmaf(vy[q],Y.z, fmaf(vz[q],Z.z, bb[q])));
            float a3 = fmaf(vx[q],X.w, fmaf(vy[q],Y.w, fmaf(vz[q],Z.w, bb[q])));
            float e0 = exp2_raw(a0);
            float e1 = exp2_raw(a1);
            float e2 = exp2_raw(a2);
            float e3 = exp2_raw(a3);
            S[q] += e0; ax[q]=fmaf(e0,X.x,ax[q]); ay[q]=fmaf(e0,Y.x,ay[q]); az[q]=fmaf(e0,Z.x,az[q]);
            S[q] += e1; ax[q]=fmaf(e1,X.y,ax[q]); ay[q]=fmaf(e1,Y.y,ay[q]); az[q]=fmaf(e1,Z.y,az[q]);
            S[q] += e2; ax[q]=fmaf(e2,X.z,ax[q]); ay[q]=fmaf(e2,Y.z,ay[q]); az[q]=fmaf(e2,Z.z,az[q]);
            S[q] += e3; ax[q]=fmaf(e3,X.w,ax[q]); ay[q]=fmaf(e3,Y.w,ay[q]); az[q]=fmaf(e3,Z.w,az[q]);
        }
    }
}

// K3: per-row softmax-weighted mean node position + fused epilogue.
// 512 blocks x 256 threads (4 waves, 4 rows/wave); nodes in SoA LDS planes
// (48 KB static); tile-1 global loads prefetched into registers under tile-0 compute.
// IDENTICAL to the round-2 version (best measured: 96.5 us total).
__global__ __launch_bounds__(256, 2) void k3_attn(
    const float* __restrict__ nodes,
    const float* __restrict__ aux, const float* __restrict__ T,
    float* __restrict__ out)
{
    __shared__ float lds[12288];   // SoA: X[0..4095], Y[4096..8191], Z[8192..12287]
    const int tid = threadIdx.x, lane = tid & 63, wv = tid >> 6;
    const int ibase = (blockIdx.x * 4 + wv) * 4;

    const float G00=aux[0],G01=aux[1],G02=aux[2];
    const float G10=aux[3],G11=aux[4],G12=aux[5];
    const float G20=aux[6],G21=aux[7],G22=aux[8];
    const float g0=aux[9],g1=aux[10],g2=aux[11];
    float C = aux[12];
    #pragma unroll
    for (int b = 1; b < 8; ++b) C = fmaxf(C, aux[12+b]);
    const float Nbound = SQRT3 * C;   // |n_j| <= sqrt(3) * max|component|

    float nx_[4], ny_[4], nz_[4], vx[4], vy[4], vz[4], bb[4];
    float S[4], ax[4], ay[4], az[4];
    #pragma unroll
    for (int q = 0; q < 4; ++q) {
        int i = ibase + q;
        float x = nodes[3*i], y = nodes[3*i+1], z = nodes[3*i+2];
        nx_[q]=x; ny_[q]=y; nz_[q]=z;
        float a = fmaf(G00,x, fmaf(G01,y, fmaf(G02,z, g0)));
        float b = fmaf(G10,x, fmaf(G11,y, fmaf(G12,z, g1)));
        float c = fmaf(G20,x, fmaf(G21,y, fmaf(G22,z, g2)));
        vx[q]=a; vy[q]=b; vz[q]=c;
        // Cauchy-Schwarz bound (log2 scale): arg <= ~0 always; shift cancels in softmax
        bb[q] = -sqrtf(fmaf(a,a, fmaf(b,b, c*c))) * Nbound;
        S[q]=0.f; ax[q]=0.f; ay[q]=0.f; az[q]=0.f;
    }

    // tile 0 stage, then ISSUE tile-1 loads before compute (waitcnt lands at write)
    float4 s0v[4][3], s1v[4][3];
    stage_load((const float4*)nodes, tid, s0v);
    stage_write(lds, tid, s0v);
    stage_load((const float4*)(nodes + 12288), tid, s1v);
    __syncthreads();
    attn_tile(lds, lane, vx, vy, vz, bb, S, ax, ay, az);
    __syncthreads();
    stage_write(lds, tid, s1v);
    __syncthreads();
    attn_tile(lds, lane, vx, vy, vz, bb, S, ax, ay, az);

    #pragma unroll
    for (int q = 0; q < 4; ++q) {
        #pragma unroll
        for (int off = 32; off; off >>= 1) {
            S[q]  += __shfl_xor(S[q],  off);
            ax[q] += __shfl_xor(ax[q], off);
            ay[q] += __shfl_xor(ay[q], off);
            az[q] += __shfl_xor(az[q], off);
        }
        float inv = 1.f / fmaxf(S[q], 1e-35f);
        ax[q] *= inv; ay[q] *= inv; az[q] *= inv;   // ā_i
    }

    // epilogue: out[i][d] = R3[d].n_i + M3[d].ā_i + h[d]; float2 stores (coalesced)
    const float4* T4 = (const float4*)T;
    #pragma unroll
    for (int t = 0; t < 4; ++t) {
        int d0 = t*128 + lane*2;
        float4 A0 = T4[2*d0+0], B0 = T4[2*d0+1];
        float4 A1 = T4[2*d0+2], B1 = T4[2*d0+3];
        #pragma unroll
        for (int q = 0; q < 4; ++q) {
            float v0 = fmaf(A0.x,nx_[q], fmaf(A0.y,ny_[q], fmaf(A0.z,nz_[q],
                       fmaf(B0.x,ax[q], fmaf(B0.y,ay[q], fmaf(B0.z,az[q], A0.w))))));
            float v1 = fmaf(A1.x,nx_[q], fmaf(A1.y,ny_[q], fmaf(A1.z,nz_[q],
                       fmaf(B1.x,ax[q], fmaf(B1.y,ay[q], fmaf(B1.z,az[q], A1.w))))));
            *(float2*)(out + (size_t)(ibase+q)*DOUT + d0) = make_float2(v0, v1);
        }
    }
}

extern "C" void kernel_launch(void* const* d_in, const int* in_sizes, int n_in,
                              void* d_out, int out_size, void* d_ws, size_t ws_size,
                              hipStream_t stream) {
    const float* nodes  = (const float*)d_in[0];
    const float* centre = (const float*)d_in[1];
    const float* Wq     = (const float*)d_in[2];
    const float* bq     = (const float*)d_in[3];
    const float* Wk     = (const float*)d_in[4];
    const float* bk     = (const float*)d_in[5];
    const float* Wv     = (const float*)d_in[6];
    const float* bv     = (const float*)d_in[7];

    float* ws  = (float*)(((uintptr_t)d_ws + 255) & ~(uintptr_t)255);
    float* aux = ws;        // 32 floats
    float* T   = ws + 64;   // 4096 floats, 256 B offset
    float* out = (float*)d_out;

    hipLaunchKernelGGL(k1_tables, dim3(148), dim3(256), 0, stream,
                       nodes, centre, Wq, bq, Wk, bk, Wv, bv, T, aux);
    hipLaunchKernelGGL(k3_attn,   dim3(512), dim3(256), 0, stream,
                       nodes, aux, T, out);
}

// Round 8
// 96.280 us; speedup vs baseline: 1.2864x; 1.0050x over previous
//
#include <hip/hip_runtime.h>

#define N_NODES 8192
#define DOUT    512
#define LOG2E   1.4426950408889634f
#define SQRT3   1.7320508075688772f

// raw v_exp_f32 (D = 2^S0) — single trans-pipe instruction
__device__ __forceinline__ float exp2_raw(float x) {
    float r;
    asm("v_exp_f32 %0, %1" : "=v"(r) : "v"(x));
    return r;
}

// ws float layout: aux[32] at 0   (G*log2e [0..8], g0*log2e [9..11], Cmax partials [12..19])
//                  T[512*8] at ws+64 (R3[3], h, M3[3], pad) — 256 B offset, 16B aligned

// ---------------- K1: T table (blocks 0..127) + aux (blocks 128..147) ----------------
// T = Wv @ B where B = [Wq3|u ; Wk3|kc] (1024 x 4+4). Each T-block builds B once in
// LDS (16 KB) from a single Wq/Wk gather pass, then streams Wv coalesced (2 MB read
// exactly once chip-wide) with conflict-free ds_read_b128 of B. 4 rows/block, 1 wave/row.
__global__ __launch_bounds__(256) void k1_tables(
    const float* __restrict__ nodes, const float* __restrict__ centre,
    const float* __restrict__ Wq, const float* __restrict__ bq,
    const float* __restrict__ Wk, const float* __restrict__ bk,
    const float* __restrict__ Wv, const float* __restrict__ bv,
    float* __restrict__ T, float* __restrict__ aux)
{
    __shared__ float4 Bq_l[512];
    __shared__ float4 Bk_l[512];
    __shared__ float red[4];
    const int tid = threadIdx.x, lane = tid & 63, wv_ = tid >> 6;
    const float c0 = centre[0], c1 = centre[1], c2 = centre[2];

    if (blockIdx.x < 128) {
        // build B tables: B_k[s] = (Wk[s,0..2], kc_s), B_q[s] = (Wq[s,0..2], u_s)
        for (int t = tid; t < 512; t += 256) {
            const float2* wk2 = (const float2*)(Wk + t*6);  // rows are 24B -> 8B aligned
            const float2* wq2 = (const float2*)(Wq + t*6);
            float2 k01 = wk2[0], k23 = wk2[1], k45 = wk2[2];
            float2 q01 = wq2[0], q23 = wq2[1], q45 = wq2[2];
            float kc = fmaf(k23.y, c0, fmaf(k45.x, c1, fmaf(k45.y, c2, bk[t])));
            float u  = fmaf(q23.y, c0, fmaf(q45.x, c1, fmaf(q45.y, c2, bq[t])));
            Bk_l[t] = make_float4(k01.x, k01.y, k23.x, kc);
            Bq_l[t] = make_float4(q01.x, q01.y, q23.x, u);
        }
        __syncthreads();

        // wave wv_ -> row r; lane-consecutive s: coalesced Wv loads (256B/wave),
        // conflict-free ds_read_b128 of B
        const int r = blockIdx.x*4 + wv_;
        const float* wvq = Wv + (size_t)r * 1024;   // Wv[r, :512]
        const float* wvk = wvq + 512;               // Wv[r, 512:]
        float m0=0.f,m1=0.f,m2=0.f,uc=0.f,r0=0.f,r1=0.f,r2=0.f,rc=0.f;
        #pragma unroll
        for (int i = 0; i < 8; ++i) {
            int s = i*64 + lane;
            float a = wvq[s];
            float b = wvk[s];
            float4 q4 = Bq_l[s];
            float4 k4 = Bk_l[s];
            m0 = fmaf(a, q4.x, m0); m1 = fmaf(a, q4.y, m1);
            m2 = fmaf(a, q4.z, m2); uc = fmaf(a, q4.w, uc);
            r0 = fmaf(b, k4.x, r0); r1 = fmaf(b, k4.y, r1);
            r2 = fmaf(b, k4.z, r2); rc = fmaf(b, k4.w, rc);
        }
        #pragma unroll
        for (int off = 32; off; off >>= 1) {
            m0 += __shfl_xor(m0, off); m1 += __shfl_xor(m1, off);
            m2 += __shfl_xor(m2, off); uc += __shfl_xor(uc, off);
            r0 += __shfl_xor(r0, off); r1 += __shfl_xor(r1, off);
            r2 += __shfl_xor(r2, off); rc += __shfl_xor(rc, off);
        }
        if (lane == 0) {
            float4 kr = Bk_l[r];   // (Wk3[r], kc_r)
            T[r*8+0] = kr.x + r0;
            T[r*8+1] = kr.y + r1;
            T[r*8+2] = kr.z + r2;
            T[r*8+3] = kr.w + rc + uc + bv[r];
            T[r*8+4] = m0; T[r*8+5] = m1; T[r*8+6] = m2; T[r*8+7] = 0.f;
        }
    } else if (blockIdx.x < 136) {
        // Cmax partial: max |component| over 1024 nodes (768 float4)
        const int b = blockIdx.x - 128;   // 0..7
        const float4* src = (const float4*)nodes + (size_t)b * 768;
        float m = 0.f;
        #pragma unroll
        for (int i = 0; i < 3; ++i) {
            float4 v = src[tid + 256*i];
            m = fmaxf(m, fmaxf(fmaxf(fabsf(v.x), fabsf(v.y)),
                               fmaxf(fabsf(v.z), fabsf(v.w))));
        }
        #pragma unroll
        for (int off = 32; off; off >>= 1) m = fmaxf(m, __shfl_xor(m, off));
        if (lane == 0) red[wv_] = m;
        __syncthreads();
        if (tid == 0)
            aux[12 + b] = fmaxf(fmaxf(red[0], red[1]), fmaxf(red[2], red[3]));
    } else {
        // G = Wq3^T Wk3 (o<9), g0 = Wq3^T kc (o=9..11), both *log2e
        const int o = blockIdx.x - 136;   // 0..11
        float acc = 0.f;
        if (o < 9) {
            int ra = o / 3, cb = o - ra*3;
            #pragma unroll
            for (int it = 0; it < 2; ++it) {
                int s = it*256 + tid;
                acc = fmaf(Wq[s*6+ra], Wk[s*6+cb], acc);
            }
        } else {
            int ra = o - 9;
            #pragma unroll
            for (int it = 0; it < 2; ++it) {
                int s = it*256 + tid;
                float kc = fmaf(Wk[s*6+3], c0, fmaf(Wk[s*6+4], c1,
                           fmaf(Wk[s*6+5], c2, bk[s])));
                acc = fmaf(Wq[s*6+ra], kc, acc);
            }
        }
        #pragma unroll
        for (int off = 32; off; off >>= 1) acc += __shfl_xor(acc, off);
        if (lane == 0) red[wv_] = acc;
        __syncthreads();
        if (tid == 0) aux[o] = (red[0]+red[1]+red[2]+red[3]) * LOG2E;
    }
}

// ---- K3 helpers: SoA staging (register transpose) + b128 inner loop ----

__device__ __forceinline__ void stage_load(const float4* __restrict__ src, int tid,
                                           float4 v[4][3]) {
    #pragma unroll
    for (int k = 0; k < 4; ++k) {
        int t = k*256 + tid;                 // triple index 0..1023
        v[k][0] = src[t*3+0];
        v[k][1] = src[t*3+1];
        v[k][2] = src[t*3+2];
    }
}

__device__ __forceinline__ void stage_write(float* __restrict__ lds, int tid,
                                            float4 v[4][3]) {
    #pragma unroll
    for (int k = 0; k < 4; ++k) {
        int t = k*256 + tid;
        float4 a = v[k][0], b = v[k][1], c = v[k][2];
        // a=(x0,y0,z0,x1) b=(y1,z1,x2,y2) c=(z2,x3,y3,z3)
        *(float4*)&lds[        t*4] = make_float4(a.x, a.w, b.z, c.y);  // X plane
        *(float4*)&lds[4096 +  t*4] = make_float4(a.y, b.x, b.w, c.z);  // Y plane
        *(float4*)&lds[8192 +  t*4] = make_float4(a.z, b.y, c.x, c.w);  // Z plane
    }
}

// inner loop over one 4096-node tile: 3 ds_read_b128 per 4 j's (vs 12 ds_read_b32)
__device__ __forceinline__ void attn_tile(const float* __restrict__ lds, int lane,
    const float vx[4], const float vy[4], const float vz[4], const float bb[4],
    float S[4], float ax[4], float ay[4], float az[4])
{
    #pragma unroll 2
    for (int it = 0; it < 16; ++it) {
        int jj = it*256 + lane*4;
        float4 X = *(const float4*)&lds[jj];
        float4 Y = *(const float4*)&lds[4096 + jj];
        float4 Z = *(const float4*)&lds[8192 + jj];
        #pragma unroll
        for (int q = 0; q < 4; ++q) {
            float a0 = fmaf(vx[q],X.x, fmaf(vy[q],Y.x, fmaf(vz[q],Z.x, bb[q])));
            float a1 = fmaf(vx[q],X.y, fmaf(vy[q],Y.y, fmaf(vz[q],Z.y, bb[q])));
            float a2 = fmaf(vx[q],X.z, fmaf(vy[q],Y.z, fmaf(vz[q],Z.z, bb[q])));
            float a3 = fmaf(vx[q],X.w, fmaf(vy[q],Y.w, fmaf(vz[q],Z.w, bb[q])));
            float e0 = exp2_raw(a0);
            float e1 = exp2_raw(a1);
            float e2 = exp2_raw(a2);
            float e3 = exp2_raw(a3);
            S[q] += e0; ax[q]=fmaf(e0,X.x,ax[q]); ay[q]=fmaf(e0,Y.x,ay[q]); az[q]=fmaf(e0,Z.x,az[q]);
            S[q] += e1; ax[q]=fmaf(e1,X.y,ax[q]); ay[q]=fmaf(e1,Y.y,ay[q]); az[q]=fmaf(e1,Z.y,az[q]);
            S[q] += e2; ax[q]=fmaf(e2,X.z,ax[q]); ay[q]=fmaf(e2,Y.z,ay[q]); az[q]=fmaf(e2,Z.z,az[q]);
            S[q] += e3; ax[q]=fmaf(e3,X.w,ax[q]); ay[q]=fmaf(e3,Y.w,ay[q]); az[q]=fmaf(e3,Z.w,az[q]);
        }
    }
}

// K3: per-row softmax-weighted mean node position + fused epilogue.
// 512 blocks x 256 threads (4 waves, 4 rows/wave); nodes in SoA LDS planes
// (48 KB static); tile-1 global loads prefetched into registers under tile-0 compute.
__global__ __launch_bounds__(256, 2) void k3_attn(
    const float* __restrict__ nodes,
    const float* __restrict__ aux, const float* __restrict__ T,
    float* __restrict__ out)
{
    __shared__ float lds[12288];   // SoA: X[0..4095], Y[4096..8191], Z[8192..12287]
    const int tid = threadIdx.x, lane = tid & 63, wv = tid >> 6;
    const int ibase = (blockIdx.x * 4 + wv) * 4;

    const float G00=aux[0],G01=aux[1],G02=aux[2];
    const float G10=aux[3],G11=aux[4],G12=aux[5];
    const float G20=aux[6],G21=aux[7],G22=aux[8];
    const float g0=aux[9],g1=aux[10],g2=aux[11];
    float C = aux[12];
    #pragma unroll
    for (int b = 1; b < 8; ++b) C = fmaxf(C, aux[12+b]);
    const float Nbound = SQRT3 * C;   // |n_j| <= sqrt(3) * max|component|

    float nx_[4], ny_[4], nz_[4], vx[4], vy[4], vz[4], bb[4];
    float S[4], ax[4], ay[4], az[4];
    #pragma unroll
    for (int q = 0; q < 4; ++q) {
        int i = ibase + q;
        float x = nodes[3*i], y = nodes[3*i+1], z = nodes[3*i+2];
        nx_[q]=x; ny_[q]=y; nz_[q]=z;
        float a = fmaf(G00,x, fmaf(G01,y, fmaf(G02,z, g0)));
        float b = fmaf(G10,x, fmaf(G11,y, fmaf(G12,z, g1)));
        float c = fmaf(G20,x, fmaf(G21,y, fmaf(G22,z, g2)));
        vx[q]=a; vy[q]=b; vz[q]=c;
        // Cauchy-Schwarz bound (log2 scale): arg <= ~0 always; shift cancels in softmax
        bb[q] = -sqrtf(fmaf(a,a, fmaf(b,b, c*c))) * Nbound;
        S[q]=0.f; ax[q]=0.f; ay[q]=0.f; az[q]=0.f;
    }

    // tile 0 stage, then ISSUE tile-1 loads before compute (waitcnt lands at write)
    float4 s0v[4][3], s1v[4][3];
    stage_load((const float4*)nodes, tid, s0v);
    stage_write(lds, tid, s0v);
    stage_load((const float4*)(nodes + 12288), tid, s1v);
    __syncthreads();
    attn_tile(lds, lane, vx, vy, vz, bb, S, ax, ay, az);
    __syncthreads();
    stage_write(lds, tid, s1v);
    __syncthreads();
    attn_tile(lds, lane, vx, vy, vz, bb, S, ax, ay, az);

    #pragma unroll
    for (int q = 0; q < 4; ++q) {
        #pragma unroll
        for (int off = 32; off; off >>= 1) {
            S[q]  += __shfl_xor(S[q],  off);
            ax[q] += __shfl_xor(ax[q], off);
            ay[q] += __shfl_xor(ay[q], off);
            az[q] += __shfl_xor(az[q], off);
        }
        float inv = 1.f / fmaxf(S[q], 1e-35f);
        ax[q] *= inv; ay[q] *= inv; az[q] *= inv;   // ā_i
    }

    // epilogue: out[i][d] = R3[d].n_i + M3[d].ā_i + h[d]; float2 stores (coalesced)
    const float4* T4 = (const float4*)T;
    #pragma unroll
    for (int t = 0; t < 4; ++t) {
        int d0 = t*128 + lane*2;
        float4 A0 = T4[2*d0+0], B0 = T4[2*d0+1];
        float4 A1 = T4[2*d0+2], B1 = T4[2*d0+3];
        #pragma unroll
        for (int q = 0; q < 4; ++q) {
            float v0 = fmaf(A0.x,nx_[q], fmaf(A0.y,ny_[q], fmaf(A0.z,nz_[q],
                       fmaf(B0.x,ax[q], fmaf(B0.y,ay[q], fmaf(B0.z,az[q], A0.w))))));
            float v1 = fmaf(A1.x,nx_[q], fmaf(A1.y,ny_[q], fmaf(A1.z,nz_[q],
                       fmaf(B1.x,ax[q], fmaf(B1.y,ay[q], fmaf(B1.z,az[q], A1.w))))));
            *(float2*)(out + (size_t)(ibase+q)*DOUT + d0) = make_float2(v0, v1);
        }
    }
}

extern "C" void kernel_launch(void* const* d_in, const int* in_sizes, int n_in,
                              void* d_out, int out_size, void* d_ws, size_t ws_size,
                              hipStream_t stream) {
    const float* nodes  = (const float*)d_in[0];
    const float* centre = (const float*)d_in[1];
    const float* Wq     = (const float*)d_in[2];
    const float* bq     = (const float*)d_in[3];
    const float* Wk     = (const float*)d_in[4];
    const float* bk     = (const float*)d_in[5];
    const float* Wv     = (const float*)d_in[6];
    const float* bv     = (const float*)d_in[7];

    float* ws  = (float*)(((uintptr_t)d_ws + 255) & ~(uintptr_t)255);
    float* aux = ws;        // 32 floats
    float* T   = ws + 64;   // 4096 floats, 256 B offset
    float* out = (float*)d_out;

    hipLaunchKernelGGL(k1_tables, dim3(148), dim3(256), 0, stream,
                       nodes, centre, Wq, bq, Wk, bk, Wv, bv, T, aux);
    hipLaunchKernelGGL(k3_attn,   dim3(512), dim3(256), 0, stream,
                       nodes, aux, T, out);
}